// Round 5
// baseline (107.311 us; speedup 1.0000x reference)
//
#include <hip/hip_runtime.h>
#include <math.h>

#define B   8
#define S   256
#define NT  50
#define E   64
#define NTE (NT * E)
#define EPSF 1e-16f
#define LOG2E 1.4426950408889634f

#define NW        4                 // waves per block
#define NTHREADS  (64 * NW)
#define LL_BLOCKS (B * S / 2)       // 1024 blocks; each handles rows (ih, S-1-ih)
#define IN_BLOCKS (B * NT)          // 400 blocks
#define NBLK      (LL_BLOCKS + IN_BLOCKS)

// Cross-block accumulators. ALL cross-block traffic is atomic RMW (fabric-
// coherent on gfx950) -> no __threadfence (no L2 writeback) needed anywhere.
// Zero-initialized at module load; the finalizing block resets them after
// consuming, so graph replays see a clean state (kernel-end = device release).
__device__ float g_ll;        // sum of log-intensities
__device__ float g_iT[B];     // per-batch sum_k sum_e softplus(...)
__device__ int   g_done;      // completion counter

__device__ __forceinline__ float softplus(float x) {
    if (x > 20.0f) return x;
    return log1pf(__expf(x));
}

__device__ __forceinline__ float wave_reduce_sum(float v) {
    #pragma unroll
    for (int off = 32; off > 0; off >>= 1)
        v += __shfl_down(v, off, 64);
    return v;  // lane 0 holds the sum
}

// ---------------------------------------------------------------------------
// Single fused kernel. Grid = NBLK, 256 threads (4 waves).
//
// LL blocks: batch b, row pair (ih, 255-ih) -> uniform 255 inner iters/block.
// Waves split each row's j-loop stride-4, with TWO independent accumulator
// chains per wave (j and j+NW interleaved) so two load streams + two exp
// chains are in flight. Inner iter: uniform ds_read_b128 (event), ds_read_b32
// (ej), 2 coalesced global loads (A,P), ~10 VALU + exp2.
//
// Integral blocks: (b,k) per block, same dual-chain structure over i.
//
// Completion: tid0 atomicAdds the block result (g_ll or g_iT[b]); the done-
// counter add is data-dependent on the returned old value, ordering it after
// the data add at the fabric. Last block computes base_sum/first/last, reads
// the accumulators via atomic loads, writes out[0], resets globals.
// ---------------------------------------------------------------------------
__global__ __launch_bounds__(NTHREADS) void main_kernel(
    const float* __restrict__ times, const int* __restrict__ types,
    const int* __restrict__ Tp,
    const float* __restrict__ emb,  const float* __restrict__ a,
    const float* __restrict__ Amat, const float* __restrict__ Pmat,
    float* __restrict__ out)
{
    const int tid = threadIdx.x;
    const int e   = tid & 63;
    const int w   = tid >> 6;
    const int bid = blockIdx.x;
    const bool is_ll = (bid < LL_BLOCKS);
    const int b = is_ll ? (bid / (S / 2)) : ((bid - LL_BLOCKS) / NT);

    __shared__ __align__(16) float  s_emb[NTE];   // 12.8 KB
    __shared__ __align__(16) float4 s_ev[S];      // (t, ty*E, ty*NTE, 0) bits
    __shared__ float s_part[2][NW][E];
    __shared__ float s_row[2];
    __shared__ int   s_fin;

    {
        const float4* __restrict__ emb4 = (const float4*)emb;
        float4* s4 = (float4*)s_emb;
        for (int idx = tid; idx < NTE / 4; idx += NTHREADS)
            s4[idx] = emb4[idx];
    }
    for (int j = tid; j < S; j += NTHREADS) {
        const int ty = types[b * S + j];
        s_ev[j] = make_float4(times[b * S + j],
                              __int_as_float(ty * E),
                              __int_as_float(ty * NTE), 0.0f);
    }
    __syncthreads();

    if (is_ll) {
        const int ih = bid % (S / 2);
        const int rows[2] = { ih, S - 1 - ih };
        #pragma unroll
        for (int r = 0; r < 2; ++r) {
            const int   i      = rows[r];
            const float t_i    = s_ev[i].x;
            const int   col    = __float_as_int(s_ev[i].y) + e;  // tyi*E + e
            const float negEi2 = -s_emb[col] * LOG2E;

            float m0 = 0.0f, m1 = 0.0f;
            int j = w;
            #pragma unroll 4
            for (; j + NW < i; j += 2 * NW) {
                const float4 ev0 = s_ev[j];
                const float4 ev1 = s_ev[j + NW];
                const int   b0   = __float_as_int(ev0.z) + col;
                const int   b1   = __float_as_int(ev1.z) + col;
                const float ej0  = s_emb[__float_as_int(ev0.y) + e];
                const float ej1  = s_emb[__float_as_int(ev1.y) + e];
                const float A0 = Amat[b0], P0 = Pmat[b0];
                const float A1 = Amat[b1], P1 = Pmat[b1];
                m0 = fmaf(A0 * ej0, exp2f(negEi2 * P0 * ej0 * (t_i - ev0.x)), m0);
                m1 = fmaf(A1 * ej1, exp2f(negEi2 * P1 * ej1 * (t_i - ev1.x)), m1);
            }
            if (j < i) {
                const float4 ev0 = s_ev[j];
                const int   b0   = __float_as_int(ev0.z) + col;
                const float ej0  = s_emb[__float_as_int(ev0.y) + e];
                m0 = fmaf(Amat[b0] * ej0,
                          exp2f(negEi2 * Pmat[b0] * ej0 * (t_i - ev0.x)), m0);
            }
            s_part[r][w][e] = m0 + m1;
        }
        __syncthreads();
        if (w < 2) {
            const int   i     = rows[w];
            const float t_i   = s_ev[i].x;
            const int   col   = __float_as_int(s_ev[i].y) + e;
            const float emb_i = s_emb[col];
            float mt = 0.0f;
            #pragma unroll
            for (int q = 0; q < NW; ++q) mt += s_part[w][q][e];
            const float sp    = softplus(fmaf(emb_i, mt, emb_i * a[col]));
            const float inten = wave_reduce_sum(sp);
            if (e == 0)
                s_row[w] = (t_i >= 0.0f) ? logf(inten + EPSF) : 0.0f;
        }
        __syncthreads();
    } else {
        const int   k      = (bid - LL_BLOCKS) % NT;
        const float Tf     = (float)(*Tp);
        const int   colk   = k * E + e;
        const float embk   = s_emb[colk];
        const float negEk2 = -embk * LOG2E;

        float a0 = 0.0f, a1 = 0.0f;
        #pragma unroll 4
        for (int i = w; i + NW < S; i += 2 * NW) {
            const float4 ev0 = s_ev[i];
            const float4 ev1 = s_ev[i + NW];
            const int   b0   = __float_as_int(ev0.z) + colk;
            const int   b1   = __float_as_int(ev1.z) + colk;
            const float e0   = s_emb[__float_as_int(ev0.y) + e];
            const float e1   = s_emb[__float_as_int(ev1.y) + e];
            const float c0 = Amat[b0] * e0 * exp2f(negEk2 * Pmat[b0] * e0 * (Tf - ev0.x));
            const float c1 = Amat[b1] * e1 * exp2f(negEk2 * Pmat[b1] * e1 * (Tf - ev1.x));
            a0 += (ev0.x >= 0.0f) ? c0 : 0.0f;
            a1 += (ev1.x >= 0.0f) ? c1 : 0.0f;
        }
        s_part[0][w][e] = a0 + a1;
        __syncthreads();
        if (w == 0) {
            float mt = 0.0f;
            #pragma unroll
            for (int q = 0; q < NW; ++q) mt += s_part[0][q][e];
            const float sp = softplus(fmaf(embk, mt, embk * a[colk]));
            const float ss = wave_reduce_sum(sp);
            if (e == 0) s_row[0] = ss;
        }
        __syncthreads();
    }

    // ---- completion protocol: atomic-only, fence-free --------------------
    if (tid == 0) {
        const float v   = is_ll ? (s_row[0] + s_row[1]) : s_row[0];
        float* dst      = is_ll ? &g_ll : &g_iT[b];
        float old = atomicAdd(dst, v);
        asm volatile("" :: "v"(old));   // data-dep: wait for data-add to complete
        const int prev = atomicAdd(&g_done, 1);
        s_fin = (prev == NBLK - 1) ? 1 : 0;
    }
    __syncthreads();
    if (!s_fin) return;

    // ---- epilogue: exactly one block, all 256 threads --------------------
    const float Tf = (float)(*Tp);

    float bs = 0.0f;
    for (int idx = tid; idx < NTE; idx += NTHREADS)
        bs += softplus(s_emb[idx] * a[idx]);

    __shared__ float red2[NTHREADS];
    red2[tid] = bs;

    __shared__ float s_first[B], s_lastt[B], s_any[B];
    for (int bb = w; bb < B; bb += NW) {
        float mn = 1e30f, mx = -1e30f;
        #pragma unroll
        for (int q = 0; q < S / 64; ++q) {
            const float tv = times[bb * S + q * 64 + e];
            const bool valid = (tv >= 0.0f);
            mn = fminf(mn, valid ? tv : 1e30f);
            mx = fmaxf(mx, valid ? tv : -1e30f);
        }
        #pragma unroll
        for (int off = 32; off > 0; off >>= 1) {
            mn = fminf(mn, __shfl_down(mn, off, 64));
            mx = fmaxf(mx, __shfl_down(mx, off, 64));
        }
        if (e == 0) {
            const bool any_valid = (mn < 1e29f);
            s_any[bb]   = any_valid ? 1.0f : 0.0f;
            s_first[bb] = any_valid ? mn : 0.0f;
            s_lastt[bb] = any_valid ? mx : 0.0f;
        }
    }
    __syncthreads();

    for (int off = 128; off > 0; off >>= 1) {
        if (tid < off) red2[tid] += red2[tid + off];
        __syncthreads();
    }

    if (tid == 0) {
        const float base_sum = red2[0];
        const float ll = atomicAdd(&g_ll, 0.0f);   // coherent read
        float integral = 0.0f;
        #pragma unroll
        for (int bb = 0; bb < B; ++bb) {
            const float iT = atomicAdd(&g_iT[bb], 0.0f);
            integral += (s_any[bb] > 0.5f)
                ? iT * (Tf - s_lastt[bb]) + base_sum * s_first[bb]
                : base_sum * Tf;
        }
        out[0] = integral - ll;
        // reset for next graph replay (kernel-end is a device-wide release)
        atomicExch(&g_ll, 0.0f);
        #pragma unroll
        for (int bb = 0; bb < B; ++bb) atomicExch(&g_iT[bb], 0.0f);
        atomicExch(&g_done, 0);
    }
}

extern "C" void kernel_launch(void* const* d_in, const int* in_sizes, int n_in,
                              void* d_out, int out_size, void* d_ws, size_t ws_size,
                              hipStream_t stream) {
    const float* times = (const float*)d_in[0];
    const int*   types = (const int*)d_in[1];
    const int*   Tp    = (const int*)d_in[2];
    const float* emb   = (const float*)d_in[3];
    const float* a     = (const float*)d_in[4];
    const float* Amat  = (const float*)d_in[5];
    const float* Pmat  = (const float*)d_in[6];
    float*       out   = (float*)d_out;

    main_kernel<<<NBLK, NTHREADS, 0, stream>>>(
        times, types, Tp, emb, a, Amat, Pmat, out);
}